// Round 8
// baseline (637.198 us; speedup 1.0000x reference)
//
#include <hip/hip_runtime.h>
#include <hip/hip_bf16.h>
#include <hip/hip_cooperative_groups.h>
#include <math.h>

namespace cg = cooperative_groups;

#define N_NODES 50000
#define N_EDGES 800000
#define IN_DIM  128
#define HID_DIM 64

#define NBKT     196        // buckets of 256 nodes: bucket = node >> 8
#define BKT_CAP  5000       // max bucket edge count: mean 4092, +14 sigma safe
#define GEMM_NODES 64       // nodes per gemm block
#define NGEMM    782        // ceil(50000 / 64)
#define XS_LD    132        // xs row pad: bank stride 4, 2-way aliasing (free)
#define GRID_FUSED 1024     // target 4 blocks/CU; clamped by occupancy query

// =============== kernel 1: gemm h1b = bf16(x @ W1) ============================
// v4 register-tiled LDS GEMM (verified R5). Lane owns 4 nodes x 4 cols.
__global__ __launch_bounds__(256)
void gemm_kernel(const float* __restrict__ x, const float* __restrict__ W1,
                 __hip_bfloat16* __restrict__ h1b) {
    __shared__ float w1s[IN_DIM * HID_DIM];     // 32 KB
    __shared__ float xs[GEMM_NODES][XS_LD];     // 33.8 KB
    int tid = threadIdx.x;
    int node0 = blockIdx.x * GEMM_NODES;
    const float4* W4 = (const float4*)W1;
    float4* w1s4 = (float4*)w1s;
#pragma unroll
    for (int i = 0; i < 8; ++i) w1s4[tid + 256 * i] = W4[tid + 256 * i];
    {
        int r = tid >> 2, q = tid & 3;
        int row = node0 + r;
        if (row >= N_NODES) row = N_NODES - 1;
        const float4* xr = (const float4*)(x + (long)row * IN_DIM + q * 32);
#pragma unroll
        for (int i = 0; i < 8; ++i)
            *(float4*)&xs[r][q * 32 + i * 4] = xr[i];
    }
    __syncthreads();
    int w    = tid >> 6;
    int lane = tid & 63;
    int ng   = lane >> 2;
    int jg   = lane & 3;
    int j0   = w * 16 + jg * 4;
    float acc[4][4] = {{0.f}};
#pragma unroll 2
    for (int k = 0; k < IN_DIM; k += 4) {
        float4 wr0 = *(const float4*)&w1s[(k + 0) * HID_DIM + j0];
        float4 wr1 = *(const float4*)&w1s[(k + 1) * HID_DIM + j0];
        float4 wr2 = *(const float4*)&w1s[(k + 2) * HID_DIM + j0];
        float4 wr3 = *(const float4*)&w1s[(k + 3) * HID_DIM + j0];
#pragma unroll
        for (int i = 0; i < 4; ++i) {
            float4 xv = *(const float4*)&xs[ng + 16 * i][k];
            acc[i][0] += xv.x * wr0.x + xv.y * wr1.x + xv.z * wr2.x + xv.w * wr3.x;
            acc[i][1] += xv.x * wr0.y + xv.y * wr1.y + xv.z * wr2.y + xv.w * wr3.y;
            acc[i][2] += xv.x * wr0.z + xv.y * wr1.z + xv.z * wr2.z + xv.w * wr3.z;
            acc[i][3] += xv.x * wr0.w + xv.y * wr1.w + xv.z * wr2.w + xv.w * wr3.w;
        }
    }
#pragma unroll
    for (int i = 0; i < 4; ++i) {
        int n = node0 + ng + 16 * i;
        if (n < N_NODES) {
            __hip_bfloat16 bf[4];
            bf[0] = __float2bfloat16(acc[i][0]);
            bf[1] = __float2bfloat16(acc[i][1]);
            bf[2] = __float2bfloat16(acc[i][2]);
            bf[3] = __float2bfloat16(acc[i][3]);
            *(uint2*)&h1b[(long)n * HID_DIM + j0] = *(uint2*)bf;
        }
    }
}

// =============== kernel 2 (cooperative): hist -> scan -> scatter ->
// =============== gather1+relu+W2 -> gather2+sigmoid ===========================
__global__ __launch_bounds__(256, 4)
void fused_graph_kernel(const int* __restrict__ src, const int* __restrict__ dst,
                        const float* __restrict__ ew,
                        int* __restrict__ cnt_g, float* __restrict__ deg_g,
                        int* __restrict__ start_g, int* __restrict__ cur_g,
                        float* __restrict__ dinv, int2* __restrict__ edge_s,
                        const __hip_bfloat16* __restrict__ h1b,
                        const float* __restrict__ b1, const float* __restrict__ W2,
                        float* __restrict__ h2s, const float* __restrict__ b2,
                        float* __restrict__ out) {
    cg::grid_group grid = cg::this_grid();
    __shared__ int  sc[256];
    __shared__ int  cnt_s[256];
    __shared__ int2 meta[4][64];
    int tid = threadIdx.x;
    int bid = blockIdx.x;
    int gthread  = bid * 256 + tid;
    int nthreads = gridDim.x * 256;

    // ---- phase 1: per-node histogram (count + weighted degree) ----
    for (int e = gthread; e < N_EDGES; e += nthreads) {
        int d = dst[e];
        atomicAdd(&cnt_g[d], 1);
        atomicAdd(&deg_g[d], ew[e]);
    }
    grid.sync();

    // ---- phase 2: per-bucket exclusive scan -> start/cursor/dinv ----
    if (bid < NBKT) {
        int node = bid * 256 + tid;
        int c = (node < N_NODES) ? cnt_g[node] : 0;
        cnt_s[tid] = c; sc[tid] = c;
        __syncthreads();
#pragma unroll
        for (int off = 1; off < 256; off <<= 1) {
            int t = (tid >= off) ? sc[tid - off] : 0;
            __syncthreads();
            sc[tid] += t;
            __syncthreads();
        }
        if (node < N_NODES) {
            int st = bid * BKT_CAP + (sc[tid] - cnt_s[tid]);
            start_g[node] = st;
            cur_g[node]   = st;
            dinv[node]    = rsqrtf(1.0f + deg_g[node]);
        }
    }
    grid.sync();

    // ---- phase 3: scatter edges to node-sorted positions ----
    for (int e = gthread; e < N_EDGES; e += nthreads) {
        int d = dst[e];
        int pos = atomicAdd(&cur_g[d], 1);
        edge_s[pos] = make_int2(src[e], __float_as_int(ew[e]));
    }
    grid.sync();

    // ---- phase 4: gather L1 + finalize + relu + W2 GEMV (wave per node) ----
    {
        int wl   = tid >> 6;
        int lane = tid & 63;
        int gwave    = gthread >> 6;
        int totWaves = nthreads >> 6;
        int c0   = (lane & 31) * 2;          // column pair this lane owns
        int half = lane >> 5;                // 0: even edges, 1: odd edges
        for (int node = gwave; node < N_NODES; node += totWaves) {
            int s0 = start_g[node];
            int ctotal = cnt_g[node];
            float accA = 0.f, accB = 0.f, accA2 = 0.f, accB2 = 0.f;
            for (int done = 0; done < ctotal; done += 64) {
                int cnt = ctotal - done;
                if (cnt > 64) cnt = 64;
                if (lane < cnt) {
                    int2 m = edge_s[s0 + done + lane];
                    float w = __int_as_float(m.y) * dinv[m.x];   // fold dinv[src]
                    meta[wl][lane] = make_int2(m.x, __float_as_int(w));
                }
                __builtin_amdgcn_wave_barrier();
                int cnte = cnt & ~1;
                int j = 0;
                for (; j + 16 <= cnte; j += 16) {
                    int2 m0 = meta[wl][j +  0 + half];
                    int2 m1 = meta[wl][j +  2 + half];
                    int2 m2 = meta[wl][j +  4 + half];
                    int2 m3 = meta[wl][j +  6 + half];
                    int2 m4 = meta[wl][j +  8 + half];
                    int2 m5 = meta[wl][j + 10 + half];
                    int2 m6 = meta[wl][j + 12 + half];
                    int2 m7 = meta[wl][j + 14 + half];
                    unsigned int p0 = *(const unsigned int*)&h1b[m0.x * HID_DIM + c0];
                    unsigned int p1 = *(const unsigned int*)&h1b[m1.x * HID_DIM + c0];
                    unsigned int p2 = *(const unsigned int*)&h1b[m2.x * HID_DIM + c0];
                    unsigned int p3 = *(const unsigned int*)&h1b[m3.x * HID_DIM + c0];
                    unsigned int p4 = *(const unsigned int*)&h1b[m4.x * HID_DIM + c0];
                    unsigned int p5 = *(const unsigned int*)&h1b[m5.x * HID_DIM + c0];
                    unsigned int p6 = *(const unsigned int*)&h1b[m6.x * HID_DIM + c0];
                    unsigned int p7 = *(const unsigned int*)&h1b[m7.x * HID_DIM + c0];
                    float w0 = __int_as_float(m0.y), w1 = __int_as_float(m1.y);
                    float w2 = __int_as_float(m2.y), w3 = __int_as_float(m3.y);
                    float w4 = __int_as_float(m4.y), w5 = __int_as_float(m5.y);
                    float w6 = __int_as_float(m6.y), w7 = __int_as_float(m7.y);
                    accA  += w0 * __uint_as_float(p0 << 16);
                    accB  += w0 * __uint_as_float(p0 & 0xFFFF0000u);
                    accA2 += w1 * __uint_as_float(p1 << 16);
                    accB2 += w1 * __uint_as_float(p1 & 0xFFFF0000u);
                    accA  += w2 * __uint_as_float(p2 << 16);
                    accB  += w2 * __uint_as_float(p2 & 0xFFFF0000u);
                    accA2 += w3 * __uint_as_float(p3 << 16);
                    accB2 += w3 * __uint_as_float(p3 & 0xFFFF0000u);
                    accA  += w4 * __uint_as_float(p4 << 16);
                    accB  += w4 * __uint_as_float(p4 & 0xFFFF0000u);
                    accA2 += w5 * __uint_as_float(p5 << 16);
                    accB2 += w5 * __uint_as_float(p5 & 0xFFFF0000u);
                    accA  += w6 * __uint_as_float(p6 << 16);
                    accB  += w6 * __uint_as_float(p6 & 0xFFFF0000u);
                    accA2 += w7 * __uint_as_float(p7 << 16);
                    accB2 += w7 * __uint_as_float(p7 & 0xFFFF0000u);
                }
                for (; j + 2 <= cnte; j += 2) {
                    int2 m = meta[wl][j + half];
                    unsigned int p = *(const unsigned int*)&h1b[m.x * HID_DIM + c0];
                    accA += __int_as_float(m.y) * __uint_as_float(p << 16);
                    accB += __int_as_float(m.y) * __uint_as_float(p & 0xFFFF0000u);
                }
                if ((cnt & 1) && half == 0) {
                    int2 m = meta[wl][cnt - 1];
                    unsigned int p = *(const unsigned int*)&h1b[m.x * HID_DIM + c0];
                    accA += __int_as_float(m.y) * __uint_as_float(p << 16);
                    accB += __int_as_float(m.y) * __uint_as_float(p & 0xFFFF0000u);
                }
                __builtin_amdgcn_wave_barrier();
            }
            accA += accA2; accB += accB2;
            accA += __shfl_xor(accA, 32, 64);
            accB += __shfl_xor(accB, 32, 64);
            float di = dinv[node];
            unsigned int sp = *(const unsigned int*)&h1b[(long)node * HID_DIM + c0];
            float s0f = __uint_as_float(sp << 16);
            float s1f = __uint_as_float(sp & 0xFFFF0000u);
            float z0 = di * (accA + di * s0f) + b1[c0];
            float z1 = di * (accB + di * s1f) + b1[c0 + 1];
            float h0  = fmaxf(z0, 0.0f);
            float h1v = fmaxf(z1, 0.0f);
            float v = h0 * W2[c0] + h1v * W2[c0 + 1];
#pragma unroll
            for (int off = 16; off > 0; off >>= 1)
                v += __shfl_down(v, off, 32);
            if (lane == 0) h2s[node] = v * di;
        }
    }
    grid.sync();

    // ---- phase 5: gather L2 + sigmoid (16 lanes per node) ----
    for (int t = gthread; t < N_NODES * 16; t += nthreads) {
        int n = t >> 4;
        int sub = t & 15;
        int s0 = start_g[n];
        int cnt = cnt_g[n];
        float acc = 0.0f;
        for (int j = sub; j < cnt; j += 16) {
            int2 m = edge_s[s0 + j];
            acc += __int_as_float(m.y) * h2s[m.x];   // dinv[src] already folded
        }
#pragma unroll
        for (int off = 8; off > 0; off >>= 1)
            acc += __shfl_down(acc, off, 16);
        if (sub == 0) {
            float z = dinv[n] * (acc + h2s[n]) + b2[0];
            out[n] = 1.0f / (1.0f + expf(-z));
        }
    }
}

extern "C" void kernel_launch(void* const* d_in, const int* in_sizes, int n_in,
                              void* d_out, int out_size, void* d_ws, size_t ws_size,
                              hipStream_t stream) {
    const float* x  = (const float*)d_in[0];
    const int*   ei = (const int*)d_in[1];
    const float* ew = (const float*)d_in[2];
    const float* W1 = (const float*)d_in[3];
    const float* b1 = (const float*)d_in[4];
    const float* W2 = (const float*)d_in[5];
    const float* b2 = (const float*)d_in[6];
    float* out = (float*)d_out;

    const int* src = ei;
    const int* dst = ei + N_EDGES;

    // workspace layout
    char* ws = (char*)d_ws;
    int2*  edge_s  = (int2*)ws;              ws += (size_t)NBKT * BKT_CAP * sizeof(int2);
    ws = (char*)(((uintptr_t)ws + 127) & ~(uintptr_t)127);
    __hip_bfloat16* h1b = (__hip_bfloat16*)ws; ws += (size_t)N_NODES * HID_DIM * sizeof(__hip_bfloat16);
    int*   cnt_g   = (int*)ws;               ws += N_NODES * sizeof(int);
    float* deg_g   = (float*)ws;             ws += N_NODES * sizeof(float);   // contiguous with cnt_g
    int*   start_g = (int*)ws;               ws += N_NODES * sizeof(int);
    int*   cur_g   = (int*)ws;               ws += N_NODES * sizeof(int);
    float* dinv    = (float*)ws;             ws += N_NODES * sizeof(float);
    float* h2s     = (float*)ws;             ws += N_NODES * sizeof(float);

    // clamp cooperative grid to co-resident capacity (host query; capture-safe)
    int grid_fused = GRID_FUSED;
    {
        int blocksPerCU = 0;
        if (hipOccupancyMaxActiveBlocksPerMultiprocessor(&blocksPerCU,
                (const void*)fused_graph_kernel, 256, 0) == hipSuccess && blocksPerCU > 0) {
            int cap = blocksPerCU * 256;     // 256 CUs
            if (grid_fused > cap) grid_fused = cap;
        }
    }

    hipMemsetAsync(cnt_g, 0, 2 * N_NODES * sizeof(int), stream);   // cnt_g + deg_g
    gemm_kernel<<<NGEMM, 256, 0, stream>>>(x, W1, h1b);
    void* params[] = {(void*)&src, (void*)&dst, (void*)&ew,
                      (void*)&cnt_g, (void*)&deg_g, (void*)&start_g, (void*)&cur_g,
                      (void*)&dinv, (void*)&edge_s, (void*)&h1b,
                      (void*)&b1, (void*)&W2, (void*)&h2s, (void*)&b2, (void*)&out};
    hipLaunchCooperativeKernel((void*)fused_graph_kernel, dim3(grid_fused), dim3(256),
                               params, 0, stream);
}

// Round 10
// 376.795 us; speedup vs baseline: 1.6911x; 1.6911x over previous
//
#include <hip/hip_runtime.h>
#include <hip/hip_bf16.h>
#include <hip/hip_cooperative_groups.h>
#include <math.h>

namespace cg = cooperative_groups;

#define N_NODES 50000
#define N_EDGES 800000
#define IN_DIM  128
#define HID_DIM 64

#define NBKT     196        // buckets of 256 nodes: bucket = node >> 8
#define BKT_CAP  5000       // mean 4092, sd 64 -> +14 sigma, safe
#define NPASSC   200        // partition blocks, 4000 edges each (R5 verified)
#define EDGES_PER_PASSC (N_EDGES / NPASSC)   // 4000
#define GEMM_NODES 64       // nodes per gemm block
#define NGEMM    782        // ceil(50000 / 64)
#define XS_LD    132        // xs row pad: bank stride 4, 2-way aliasing (free)
#define GRID_FUSED 1024     // target 4 blocks/CU; clamped by occupancy query

// =============== kernel 1: fused bucket-partition (blocks 0..199) =============
// =============== + gemm h1b = bf16(x @ W1) (blocks 200..981) ==================
// EXACT R5-verified kernel (155 us config): LDS histograms, 39K gcursor
// atomics total, v4 register-tiled LDS GEMM.
__global__ __launch_bounds__(256)
void partgemm_kernel(const int* __restrict__ src, const int* __restrict__ dst,
                     const float* __restrict__ ew, int* __restrict__ gcursor,
                     int2* __restrict__ edge_b,
                     const float* __restrict__ x, const float* __restrict__ W1,
                     __hip_bfloat16* __restrict__ h1b) {
    __shared__ float w1s[IN_DIM * HID_DIM];     // 32 KB (PassC overlays counters)
    __shared__ float xs[GEMM_NODES][XS_LD];     // 33.8 KB
    int bid = blockIdx.x;
    int tid = threadIdx.x;
    if (bid < NPASSC) {
        // ---- PassC: partition into buckets ----
        int* cnt1    = (int*)w1s;            // [196]
        int* cnt2    = cnt1 + NBKT;          // [196]
        int* runbase = cnt2 + NBKT;          // [196]
        if (tid < NBKT) { cnt1[tid] = 0; cnt2[tid] = 0; }
        __syncthreads();
        int e0 = bid * EDGES_PER_PASSC;
        for (int i = tid; i < EDGES_PER_PASSC; i += 256)
            atomicAdd(&cnt1[dst[e0 + i] >> 8], 1);
        __syncthreads();
        if (tid < NBKT) {
            int c = cnt1[tid];
            runbase[tid] = (c > 0) ? atomicAdd(&gcursor[tid], c) : 0;
        }
        __syncthreads();
        for (int i = tid; i < EDGES_PER_PASSC; i += 256) {
            int e = e0 + i;
            int d = dst[e];
            int b = d >> 8;
            int lr = atomicAdd(&cnt2[b], 1);
            int pos = b * BKT_CAP + runbase[b] + lr;
            edge_b[pos] = make_int2(src[e] | ((d & 255) << 16), __float_as_int(ew[e]));
        }
        return;
    }
    // ---- gemm path (v4: register tiling) ----
    int gb = bid - NPASSC;                   // 0..781
    int node0 = gb * GEMM_NODES;
    const float4* W4 = (const float4*)W1;
    float4* w1s4 = (float4*)w1s;
#pragma unroll
    for (int i = 0; i < 8; ++i) w1s4[tid + 256 * i] = W4[tid + 256 * i];
    {
        int r = tid >> 2, q = tid & 3;
        int row = node0 + r;
        if (row >= N_NODES) row = N_NODES - 1;
        const float4* xr = (const float4*)(x + (long)row * IN_DIM + q * 32);
#pragma unroll
        for (int i = 0; i < 8; ++i)
            *(float4*)&xs[r][q * 32 + i * 4] = xr[i];
    }
    __syncthreads();
    int w    = tid >> 6;
    int lane = tid & 63;
    int ng   = lane >> 2;
    int jg   = lane & 3;
    int j0   = w * 16 + jg * 4;
    float acc[4][4] = {{0.f}};
#pragma unroll 2
    for (int k = 0; k < IN_DIM; k += 4) {
        float4 wr0 = *(const float4*)&w1s[(k + 0) * HID_DIM + j0];
        float4 wr1 = *(const float4*)&w1s[(k + 1) * HID_DIM + j0];
        float4 wr2 = *(const float4*)&w1s[(k + 2) * HID_DIM + j0];
        float4 wr3 = *(const float4*)&w1s[(k + 3) * HID_DIM + j0];
#pragma unroll
        for (int i = 0; i < 4; ++i) {
            float4 xv = *(const float4*)&xs[ng + 16 * i][k];
            acc[i][0] += xv.x * wr0.x + xv.y * wr1.x + xv.z * wr2.x + xv.w * wr3.x;
            acc[i][1] += xv.x * wr0.y + xv.y * wr1.y + xv.z * wr2.y + xv.w * wr3.y;
            acc[i][2] += xv.x * wr0.z + xv.y * wr1.z + xv.z * wr2.z + xv.w * wr3.z;
            acc[i][3] += xv.x * wr0.w + xv.y * wr1.w + xv.z * wr2.w + xv.w * wr3.w;
        }
    }
#pragma unroll
    for (int i = 0; i < 4; ++i) {
        int n = node0 + ng + 16 * i;
        if (n < N_NODES) {
            __hip_bfloat16 bf[4];
            bf[0] = __float2bfloat16(acc[i][0]);
            bf[1] = __float2bfloat16(acc[i][1]);
            bf[2] = __float2bfloat16(acc[i][2]);
            bf[3] = __float2bfloat16(acc[i][3]);
            *(uint2*)&h1b[(long)n * HID_DIM + j0] = *(uint2*)bf;
        }
    }
}

// =============== kernel 2 (cooperative): bsort -> gather1 -> gather2 ==========
// R5's verified bsort/gather1/gather2 bodies, phase-looped with grid.sync().
// NO raw per-edge global atomics (the R7 fused kernel's 616us mistake) —
// counting/scan stay in LDS; only normal stores cross phases.
__global__ __launch_bounds__(256, 4)
void fused_post_kernel(const int* __restrict__ gcursor, const int2* __restrict__ edge_b,
                       int2* __restrict__ edge_s, int* __restrict__ start_g,
                       int* __restrict__ cnt_g, float* __restrict__ dinv,
                       const __hip_bfloat16* __restrict__ h1b,
                       const float* __restrict__ b1, const float* __restrict__ W2,
                       float* __restrict__ h2s, const float* __restrict__ b2,
                       float* __restrict__ out) {
    cg::grid_group grid = cg::this_grid();
    __shared__ int   cnt[256];
    __shared__ int   cnt2[256];
    __shared__ float deg[256];
    __shared__ int   sc[256];
    __shared__ int2  meta[4][64];
    int tid = threadIdx.x;
    int bid = blockIdx.x;
    int gthread  = bid * 256 + tid;
    int nthreads = gridDim.x * 256;

    // ---- phase A: per-bucket fine sort + start/cnt/dinv (block b = bucket b) --
    if (bid < NBKT) {
        int M    = gcursor[bid];
        int base = bid * BKT_CAP;
        cnt[tid] = 0; cnt2[tid] = 0; deg[tid] = 0.0f;
        __syncthreads();
        for (int i = tid; i < M; i += 256) {
            int2 e = edge_b[base + i];
            int ld = (e.x >> 16) & 255;
            atomicAdd(&cnt[ld], 1);
            atomicAdd(&deg[ld], __int_as_float(e.y));
        }
        __syncthreads();
        sc[tid] = cnt[tid];
        __syncthreads();
#pragma unroll
        for (int off = 1; off < 256; off <<= 1) {
            int t = (tid >= off) ? sc[tid - off] : 0;
            __syncthreads();
            sc[tid] += t;
            __syncthreads();
        }
        int startL = sc[tid] - cnt[tid];     // exclusive
        int node = bid * 256 + tid;
        if (node < N_NODES) {
            start_g[node] = base + startL;
            cnt_g[node]   = cnt[tid];
            dinv[node]    = rsqrtf(1.0f + deg[tid]);
        }
        sc[tid] = startL;
        __syncthreads();
        for (int i = tid; i < M; i += 256) {
            int2 e = edge_b[base + i];
            int ld = (e.x >> 16) & 255;
            int r = atomicAdd(&cnt2[ld], 1);
            edge_s[base + sc[ld] + r] = make_int2(e.x & 0xFFFF, e.y);
        }
    }
    grid.sync();

    // ---- phase B: gather L1 + finalize + relu + W2 GEMV (wave per node) ----
    {
        int wl   = tid >> 6;
        int lane = tid & 63;
        int gwave    = gthread >> 6;
        int totWaves = nthreads >> 6;
        int c0   = (lane & 31) * 2;          // column pair this lane owns
        int half = lane >> 5;                // 0: even edges, 1: odd edges
        for (int node = gwave; node < N_NODES; node += totWaves) {
            int s0 = start_g[node];
            int ctotal = cnt_g[node];
            float accA = 0.f, accB = 0.f, accA2 = 0.f, accB2 = 0.f;
            for (int done = 0; done < ctotal; done += 64) {
                int cnt_ = ctotal - done;
                if (cnt_ > 64) cnt_ = 64;
                if (lane < cnt_) {
                    int2 m = edge_s[s0 + done + lane];
                    float w = __int_as_float(m.y) * dinv[m.x];   // fold dinv[src]
                    meta[wl][lane] = make_int2(m.x, __float_as_int(w));
                }
                __builtin_amdgcn_wave_barrier();
                int cnte = cnt_ & ~1;
                int j = 0;
                for (; j + 16 <= cnte; j += 16) {
                    int2 m0 = meta[wl][j +  0 + half];
                    int2 m1 = meta[wl][j +  2 + half];
                    int2 m2 = meta[wl][j +  4 + half];
                    int2 m3 = meta[wl][j +  6 + half];
                    int2 m4 = meta[wl][j +  8 + half];
                    int2 m5 = meta[wl][j + 10 + half];
                    int2 m6 = meta[wl][j + 12 + half];
                    int2 m7 = meta[wl][j + 14 + half];
                    unsigned int p0 = *(const unsigned int*)&h1b[m0.x * HID_DIM + c0];
                    unsigned int p1 = *(const unsigned int*)&h1b[m1.x * HID_DIM + c0];
                    unsigned int p2 = *(const unsigned int*)&h1b[m2.x * HID_DIM + c0];
                    unsigned int p3 = *(const unsigned int*)&h1b[m3.x * HID_DIM + c0];
                    unsigned int p4 = *(const unsigned int*)&h1b[m4.x * HID_DIM + c0];
                    unsigned int p5 = *(const unsigned int*)&h1b[m5.x * HID_DIM + c0];
                    unsigned int p6 = *(const unsigned int*)&h1b[m6.x * HID_DIM + c0];
                    unsigned int p7 = *(const unsigned int*)&h1b[m7.x * HID_DIM + c0];
                    float w0 = __int_as_float(m0.y), w1 = __int_as_float(m1.y);
                    float w2 = __int_as_float(m2.y), w3 = __int_as_float(m3.y);
                    float w4 = __int_as_float(m4.y), w5 = __int_as_float(m5.y);
                    float w6 = __int_as_float(m6.y), w7 = __int_as_float(m7.y);
                    accA  += w0 * __uint_as_float(p0 << 16);
                    accB  += w0 * __uint_as_float(p0 & 0xFFFF0000u);
                    accA2 += w1 * __uint_as_float(p1 << 16);
                    accB2 += w1 * __uint_as_float(p1 & 0xFFFF0000u);
                    accA  += w2 * __uint_as_float(p2 << 16);
                    accB  += w2 * __uint_as_float(p2 & 0xFFFF0000u);
                    accA2 += w3 * __uint_as_float(p3 << 16);
                    accB2 += w3 * __uint_as_float(p3 & 0xFFFF0000u);
                    accA  += w4 * __uint_as_float(p4 << 16);
                    accB  += w4 * __uint_as_float(p4 & 0xFFFF0000u);
                    accA2 += w5 * __uint_as_float(p5 << 16);
                    accB2 += w5 * __uint_as_float(p5 & 0xFFFF0000u);
                    accA  += w6 * __uint_as_float(p6 << 16);
                    accB  += w6 * __uint_as_float(p6 & 0xFFFF0000u);
                    accA2 += w7 * __uint_as_float(p7 << 16);
                    accB2 += w7 * __uint_as_float(p7 & 0xFFFF0000u);
                }
                for (; j + 2 <= cnte; j += 2) {
                    int2 m = meta[wl][j + half];
                    unsigned int p = *(const unsigned int*)&h1b[m.x * HID_DIM + c0];
                    accA += __int_as_float(m.y) * __uint_as_float(p << 16);
                    accB += __int_as_float(m.y) * __uint_as_float(p & 0xFFFF0000u);
                }
                if ((cnt_ & 1) && half == 0) {
                    int2 m = meta[wl][cnt_ - 1];
                    unsigned int p = *(const unsigned int*)&h1b[m.x * HID_DIM + c0];
                    accA += __int_as_float(m.y) * __uint_as_float(p << 16);
                    accB += __int_as_float(m.y) * __uint_as_float(p & 0xFFFF0000u);
                }
                __builtin_amdgcn_wave_barrier();
            }
            accA += accA2; accB += accB2;
            accA += __shfl_xor(accA, 32, 64);
            accB += __shfl_xor(accB, 32, 64);
            float di = dinv[node];
            unsigned int sp = *(const unsigned int*)&h1b[(long)node * HID_DIM + c0];
            float s0f = __uint_as_float(sp << 16);
            float s1f = __uint_as_float(sp & 0xFFFF0000u);
            float z0 = di * (accA + di * s0f) + b1[c0];
            float z1 = di * (accB + di * s1f) + b1[c0 + 1];
            float h0  = fmaxf(z0, 0.0f);
            float h1v = fmaxf(z1, 0.0f);
            float v = h0 * W2[c0] + h1v * W2[c0 + 1];
#pragma unroll
            for (int off = 16; off > 0; off >>= 1)
                v += __shfl_down(v, off, 32);
            if (lane == 0) h2s[node] = v * di;
        }
    }
    grid.sync();

    // ---- phase C: gather L2 + sigmoid (16 lanes per node) ----
    for (int t = gthread; t < N_NODES * 16; t += nthreads) {
        int n = t >> 4;
        int sub = t & 15;
        int s0 = start_g[n];
        int cnt_ = cnt_g[n];
        float acc = 0.0f;
        for (int j = sub; j < cnt_; j += 16) {
            int2 m = edge_s[s0 + j];
            acc += __int_as_float(m.y) * h2s[m.x];   // dinv[src] already folded
        }
#pragma unroll
        for (int off = 8; off > 0; off >>= 1)
            acc += __shfl_down(acc, off, 16);
        if (sub == 0) {
            float z = dinv[n] * (acc + h2s[n]) + b2[0];
            out[n] = 1.0f / (1.0f + expf(-z));
        }
    }
}

extern "C" void kernel_launch(void* const* d_in, const int* in_sizes, int n_in,
                              void* d_out, int out_size, void* d_ws, size_t ws_size,
                              hipStream_t stream) {
    const float* x  = (const float*)d_in[0];
    const int*   ei = (const int*)d_in[1];
    const float* ew = (const float*)d_in[2];
    const float* W1 = (const float*)d_in[3];
    const float* b1 = (const float*)d_in[4];
    const float* W2 = (const float*)d_in[5];
    const float* b2 = (const float*)d_in[6];
    float* out = (float*)d_out;

    const int* src = ei;
    const int* dst = ei + N_EDGES;

    // workspace layout (int2 arrays first for 8B alignment)
    char* ws = (char*)d_ws;
    int2*  edge_b  = (int2*)ws;              ws += (size_t)NBKT * BKT_CAP * sizeof(int2);
    int2*  edge_s  = (int2*)ws;              ws += (size_t)NBKT * BKT_CAP * sizeof(int2);
    int*   gcursor = (int*)ws;               ws += NBKT * sizeof(int);
    int*   start_g = (int*)ws;               ws += N_NODES * sizeof(int);
    int*   cnt_g   = (int*)ws;               ws += N_NODES * sizeof(int);
    float* dinv    = (float*)ws;             ws += N_NODES * sizeof(float);
    float* h2s     = (float*)ws;             ws += N_NODES * sizeof(float);
    // align h1b to 128 B so each 64xbf16 row sits in a single cache line
    ws = (char*)(((uintptr_t)ws + 127) & ~(uintptr_t)127);
    __hip_bfloat16* h1b = (__hip_bfloat16*)ws;  // N_NODES * HID_DIM bf16

    // clamp cooperative grid to co-resident capacity (host query; capture-safe)
    int grid_fused = GRID_FUSED;
    {
        int blocksPerCU = 0;
        if (hipOccupancyMaxActiveBlocksPerMultiprocessor(&blocksPerCU,
                (const void*)fused_post_kernel, 256, 0) == hipSuccess && blocksPerCU > 0) {
            int cap = blocksPerCU * 256;     // 256 CUs
            if (grid_fused > cap) grid_fused = cap;
        }
    }

    hipMemsetAsync(gcursor, 0, NBKT * sizeof(int), stream);
    partgemm_kernel<<<NPASSC + NGEMM, 256, 0, stream>>>(src, dst, ew, gcursor, edge_b, x, W1, h1b);
    void* params[] = {(void*)&gcursor, (void*)&edge_b, (void*)&edge_s,
                      (void*)&start_g, (void*)&cnt_g, (void*)&dinv, (void*)&h1b,
                      (void*)&b1, (void*)&W2, (void*)&h2s, (void*)&b2, (void*)&out};
    hipLaunchCooperativeKernel((void*)fused_post_kernel, dim3(grid_fused), dim3(256),
                               params, 0, stream);
}

// Round 11
// 158.366 us; speedup vs baseline: 4.0236x; 2.3793x over previous
//
#include <hip/hip_runtime.h>
#include <hip/hip_bf16.h>
#include <math.h>

#define N_NODES 50000
#define N_EDGES 800000
#define IN_DIM  128
#define HID_DIM 64

#define NBKT     196        // buckets of 256 nodes: bucket = node >> 8
#define BKT_CAP  5000       // edge_s per-bucket capacity: mean 4082, +14 sigma safe
#define NPASSC   200        // partition blocks, 4000 edges each
#define EDGES_PER_PASSC (N_EDGES / NPASSC)   // 4000
#define GEMM_NODES 64       // nodes per gemm block
#define NGEMM    782        // ceil(50000 / 64)
#define XS_LD    132        // xs row pad: bank stride 4, 2-way aliasing (free)

// =============== kernel 1: local-sort partition (blocks 0..199) ===============
// =============== + gemm h1b = bf16(x @ W1) (blocks 200..981) ==================
// PassC v3: ZERO global atomics. Block bid counting-sorts its 4000 edges by
// bucket into its own segment edge_b[bid*4000..], and writes per-(block,bucket)
// count/offset tables with plain stores (every entry written -> no memset).
// gemm v4 unchanged (register-tiled LDS GEMM, R5-verified).
__global__ __launch_bounds__(256)
void partgemm_kernel(const int* __restrict__ src, const int* __restrict__ dst,
                     const float* __restrict__ ew,
                     int* __restrict__ cnt2d, int* __restrict__ off2d,
                     int2* __restrict__ edge_b,
                     const float* __restrict__ x, const float* __restrict__ W1,
                     __hip_bfloat16* __restrict__ h1b) {
    __shared__ float w1s[IN_DIM * HID_DIM];     // 32 KB (PassC overlays counters)
    __shared__ float xs[GEMM_NODES][XS_LD];     // 33.8 KB
    int bid = blockIdx.x;
    int tid = threadIdx.x;
    if (bid < NPASSC) {
        // ---- PassC: local counting sort into own segment ----
        int* cnt1   = (int*)w1s;             // [256] (196 used, rest 0 for scan)
        int* cnt2   = cnt1 + 256;            // [256]
        int* runoff = cnt2 + 256;            // [196] exclusive offsets
        int* scuf   = runoff + 256;          // [256] scan buffer
        cnt1[tid] = 0; cnt2[tid] = 0;
        __syncthreads();
        int e0 = bid * EDGES_PER_PASSC;
        for (int i = tid; i < EDGES_PER_PASSC; i += 256)
            atomicAdd(&cnt1[dst[e0 + i] >> 8], 1);
        __syncthreads();
        scuf[tid] = cnt1[tid];
        __syncthreads();
#pragma unroll
        for (int off = 1; off < 256; off <<= 1) {
            int t = (tid >= off) ? scuf[tid - off] : 0;
            __syncthreads();
            scuf[tid] += t;
            __syncthreads();
        }
        int excl = scuf[tid] - cnt1[tid];    // exclusive prefix
        if (tid < NBKT) {
            runoff[tid] = excl;
            cnt2d[bid * NBKT + tid] = cnt1[tid];   // plain stores, no atomics
            off2d[bid * NBKT + tid] = excl;
        }
        __syncthreads();
        for (int i = tid; i < EDGES_PER_PASSC; i += 256) {
            int e = e0 + i;
            int d = dst[e];
            int b = d >> 8;
            int lr = atomicAdd(&cnt2[b], 1);       // LDS atomic only
            int pos = bid * EDGES_PER_PASSC + runoff[b] + lr;  // segment-local
            edge_b[pos] = make_int2(src[e] | ((d & 255) << 16), __float_as_int(ew[e]));
        }
        return;
    }
    // ---- gemm path (v4: register tiling, R5-verified) ----
    int gb = bid - NPASSC;                   // 0..781
    int node0 = gb * GEMM_NODES;
    const float4* W4 = (const float4*)W1;
    float4* w1s4 = (float4*)w1s;
#pragma unroll
    for (int i = 0; i < 8; ++i) w1s4[tid + 256 * i] = W4[tid + 256 * i];
    {
        int r = tid >> 2, q = tid & 3;
        int row = node0 + r;
        if (row >= N_NODES) row = N_NODES - 1;
        const float4* xr = (const float4*)(x + (long)row * IN_DIM + q * 32);
#pragma unroll
        for (int i = 0; i < 8; ++i)
            *(float4*)&xs[r][q * 32 + i * 4] = xr[i];
    }
    __syncthreads();
    int w    = tid >> 6;
    int lane = tid & 63;
    int ng   = lane >> 2;
    int jg   = lane & 3;
    int j0   = w * 16 + jg * 4;
    float acc[4][4] = {{0.f}};
#pragma unroll 2
    for (int k = 0; k < IN_DIM; k += 4) {
        float4 wr0 = *(const float4*)&w1s[(k + 0) * HID_DIM + j0];
        float4 wr1 = *(const float4*)&w1s[(k + 1) * HID_DIM + j0];
        float4 wr2 = *(const float4*)&w1s[(k + 2) * HID_DIM + j0];
        float4 wr3 = *(const float4*)&w1s[(k + 3) * HID_DIM + j0];
#pragma unroll
        for (int i = 0; i < 4; ++i) {
            float4 xv = *(const float4*)&xs[ng + 16 * i][k];
            acc[i][0] += xv.x * wr0.x + xv.y * wr1.x + xv.z * wr2.x + xv.w * wr3.x;
            acc[i][1] += xv.x * wr0.y + xv.y * wr1.y + xv.z * wr2.y + xv.w * wr3.y;
            acc[i][2] += xv.x * wr0.z + xv.y * wr1.z + xv.z * wr2.z + xv.w * wr3.z;
            acc[i][3] += xv.x * wr0.w + xv.y * wr1.w + xv.z * wr2.w + xv.w * wr3.w;
        }
    }
#pragma unroll
    for (int i = 0; i < 4; ++i) {
        int n = node0 + ng + 16 * i;
        if (n < N_NODES) {
            __hip_bfloat16 bf[4];
            bf[0] = __float2bfloat16(acc[i][0]);
            bf[1] = __float2bfloat16(acc[i][1]);
            bf[2] = __float2bfloat16(acc[i][2]);
            bf[3] = __float2bfloat16(acc[i][3]);
            *(uint2*)&h1b[(long)n * HID_DIM + j0] = *(uint2*)bf;
        }
    }
}

// =============== kernel 2: per-bucket fine sort + start/cnt/dinv ==============
// Bucket b's edges live in 200 fragments (one per PassC segment). Prefix-sum
// the fragment counts, then fetch edge i via 8-step LDS binary search.
// Downstream layout (edge_s, start/cnt/dinv) identical to R5.
__global__ __launch_bounds__(1024)
void bsort_kernel(const int* __restrict__ cnt2d, const int* __restrict__ off2d,
                  const int2* __restrict__ edge_b,
                  int2* __restrict__ edge_s, int* __restrict__ start_g,
                  int* __restrict__ cnt_g, float* __restrict__ dinv) {
    __shared__ int   cnt[256];
    __shared__ int   cnt2[256];
    __shared__ float deg[256];
    __shared__ int   sc[256];
    __shared__ int   fragbase[NPASSC + 1];   // exclusive prefix + total
    __shared__ int   fragoff[NPASSC];
    int b   = blockIdx.x;
    int tid = threadIdx.x;
    int base = b * BKT_CAP;
    if (tid < 256) { cnt[tid] = 0; cnt2[tid] = 0; deg[tid] = 0.0f; }
    // fragment counts/offsets for this bucket
    int fc = 0;
    if (tid < NPASSC) {
        fc = cnt2d[tid * NBKT + b];
        fragoff[tid] = off2d[tid * NBKT + b];
    }
    if (tid < 256) sc[tid] = fc;             // tid in [NPASSC,256) -> 0
    __syncthreads();
#pragma unroll
    for (int off = 1; off < 256; off <<= 1) {
        int t = (tid >= off && tid < 256) ? sc[tid - off] : 0;
        __syncthreads();
        if (tid < 256) sc[tid] += t;
        __syncthreads();
    }
    if (tid < NPASSC) fragbase[tid] = sc[tid] - fc;          // exclusive
    if (tid == NPASSC - 1) fragbase[NPASSC] = sc[tid];       // total M
    __syncthreads();
    int M = fragbase[NPASSC];
    // pass 1: per-node count + weighted degree
    for (int i = tid; i < M; i += 1024) {
        int lo = 0, hi = NPASSC - 1;
        while (lo < hi) { int mid = (lo + hi + 1) >> 1; if (fragbase[mid] <= i) lo = mid; else hi = mid - 1; }
        int2 e = edge_b[lo * EDGES_PER_PASSC + fragoff[lo] + (i - fragbase[lo])];
        int ld = (e.x >> 16) & 255;
        atomicAdd(&cnt[ld], 1);
        atomicAdd(&deg[ld], __int_as_float(e.y));
    }
    __syncthreads();
    // exclusive scan of cnt over 256
    if (tid < 256) sc[tid] = cnt[tid];
    __syncthreads();
#pragma unroll
    for (int off = 1; off < 256; off <<= 1) {
        int t = (tid >= off && tid < 256) ? sc[tid - off] : 0;
        __syncthreads();
        if (tid < 256) sc[tid] += t;
        __syncthreads();
    }
    if (tid < 256) {
        int startL = sc[tid] - cnt[tid];     // exclusive
        int node = b * 256 + tid;
        if (node < N_NODES) {
            start_g[node] = base + startL;
            cnt_g[node]   = cnt[tid];
            dinv[node]    = rsqrtf(1.0f + deg[tid]);
        }
        sc[tid] = startL;                    // stash exclusive offsets for scatter
    }
    __syncthreads();
    // pass 2: scatter node-sorted
    for (int i = tid; i < M; i += 1024) {
        int lo = 0, hi = NPASSC - 1;
        while (lo < hi) { int mid = (lo + hi + 1) >> 1; if (fragbase[mid] <= i) lo = mid; else hi = mid - 1; }
        int2 e = edge_b[lo * EDGES_PER_PASSC + fragoff[lo] + (i - fragbase[lo])];
        int ld = (e.x >> 16) & 255;
        int r = atomicAdd(&cnt2[ld], 1);
        edge_s[base + sc[ld] + r] = make_int2(e.x & 0xFFFF, e.y);
    }
}

// =============== kernel 3: gather L1 + finalize + relu + W2 GEMV ==============
// R5-verified body. Wave per node; lane l owns column pair {2(l&31), 2(l&31)+1};
// lanes 0-31 even edges, 32-63 odd edges. bf16->f32 via bit shift.
__global__ void gather1_layer2_kernel(const int* __restrict__ start_g, const int* __restrict__ cnt_g,
                                      const int2* __restrict__ edge_s,
                                      const __hip_bfloat16* __restrict__ h1b,
                                      const float* __restrict__ dinv, const float* __restrict__ b1,
                                      const float* __restrict__ W2, float* __restrict__ h2s) {
    __shared__ int2 meta[4][64];
    int wave = (blockIdx.x * blockDim.x + threadIdx.x) >> 6;
    int wl = threadIdx.x >> 6;
    int lane = threadIdx.x & 63;
    if (wave >= N_NODES) return;
    int s0 = start_g[wave];
    int ctotal = cnt_g[wave];
    int c0 = (lane & 31) * 2;
    int half = lane >> 5;
    float accA = 0.f, accB = 0.f, accA2 = 0.f, accB2 = 0.f;
    for (int done = 0; done < ctotal; done += 64) {
        int cnt = ctotal - done;
        if (cnt > 64) cnt = 64;
        if (lane < cnt) {
            int2 m = edge_s[s0 + done + lane];
            float w = __int_as_float(m.y) * dinv[m.x];
            meta[wl][lane] = make_int2(m.x, __float_as_int(w));
        }
        __builtin_amdgcn_wave_barrier();
        int cnte = cnt & ~1;
        int j = 0;
        for (; j + 16 <= cnte; j += 16) {
            int2 m0 = meta[wl][j +  0 + half];
            int2 m1 = meta[wl][j +  2 + half];
            int2 m2 = meta[wl][j +  4 + half];
            int2 m3 = meta[wl][j +  6 + half];
            int2 m4 = meta[wl][j +  8 + half];
            int2 m5 = meta[wl][j + 10 + half];
            int2 m6 = meta[wl][j + 12 + half];
            int2 m7 = meta[wl][j + 14 + half];
            unsigned int p0 = *(const unsigned int*)&h1b[m0.x * HID_DIM + c0];
            unsigned int p1 = *(const unsigned int*)&h1b[m1.x * HID_DIM + c0];
            unsigned int p2 = *(const unsigned int*)&h1b[m2.x * HID_DIM + c0];
            unsigned int p3 = *(const unsigned int*)&h1b[m3.x * HID_DIM + c0];
            unsigned int p4 = *(const unsigned int*)&h1b[m4.x * HID_DIM + c0];
            unsigned int p5 = *(const unsigned int*)&h1b[m5.x * HID_DIM + c0];
            unsigned int p6 = *(const unsigned int*)&h1b[m6.x * HID_DIM + c0];
            unsigned int p7 = *(const unsigned int*)&h1b[m7.x * HID_DIM + c0];
            float w0 = __int_as_float(m0.y), w1 = __int_as_float(m1.y);
            float w2 = __int_as_float(m2.y), w3 = __int_as_float(m3.y);
            float w4 = __int_as_float(m4.y), w5 = __int_as_float(m5.y);
            float w6 = __int_as_float(m6.y), w7 = __int_as_float(m7.y);
            accA  += w0 * __uint_as_float(p0 << 16);
            accB  += w0 * __uint_as_float(p0 & 0xFFFF0000u);
            accA2 += w1 * __uint_as_float(p1 << 16);
            accB2 += w1 * __uint_as_float(p1 & 0xFFFF0000u);
            accA  += w2 * __uint_as_float(p2 << 16);
            accB  += w2 * __uint_as_float(p2 & 0xFFFF0000u);
            accA2 += w3 * __uint_as_float(p3 << 16);
            accB2 += w3 * __uint_as_float(p3 & 0xFFFF0000u);
            accA  += w4 * __uint_as_float(p4 << 16);
            accB  += w4 * __uint_as_float(p4 & 0xFFFF0000u);
            accA2 += w5 * __uint_as_float(p5 << 16);
            accB2 += w5 * __uint_as_float(p5 & 0xFFFF0000u);
            accA  += w6 * __uint_as_float(p6 << 16);
            accB  += w6 * __uint_as_float(p6 & 0xFFFF0000u);
            accA2 += w7 * __uint_as_float(p7 << 16);
            accB2 += w7 * __uint_as_float(p7 & 0xFFFF0000u);
        }
        for (; j + 2 <= cnte; j += 2) {
            int2 m = meta[wl][j + half];
            unsigned int p = *(const unsigned int*)&h1b[m.x * HID_DIM + c0];
            accA += __int_as_float(m.y) * __uint_as_float(p << 16);
            accB += __int_as_float(m.y) * __uint_as_float(p & 0xFFFF0000u);
        }
        if ((cnt & 1) && half == 0) {
            int2 m = meta[wl][cnt - 1];
            unsigned int p = *(const unsigned int*)&h1b[m.x * HID_DIM + c0];
            accA += __int_as_float(m.y) * __uint_as_float(p << 16);
            accB += __int_as_float(m.y) * __uint_as_float(p & 0xFFFF0000u);
        }
        __builtin_amdgcn_wave_barrier();
    }
    accA += accA2; accB += accB2;
    accA += __shfl_xor(accA, 32, 64);
    accB += __shfl_xor(accB, 32, 64);
    float di = dinv[wave];
    unsigned int sp = *(const unsigned int*)&h1b[wave * HID_DIM + c0];
    float s0f = __uint_as_float(sp << 16);
    float s1f = __uint_as_float(sp & 0xFFFF0000u);
    float z0 = di * (accA + di * s0f) + b1[c0];
    float z1 = di * (accB + di * s1f) + b1[c0 + 1];
    float h0  = fmaxf(z0, 0.0f);
    float h1v = fmaxf(z1, 0.0f);
    float v = h0 * W2[c0] + h1v * W2[c0 + 1];
#pragma unroll
    for (int off = 16; off > 0; off >>= 1)
        v += __shfl_down(v, off, 32);
    if (lane == 0) h2s[wave] = v * di;
}

// =============== kernel 4: gather L2 + sigmoid ================================
__global__ void gather2_final_kernel(const int* __restrict__ start_g, const int* __restrict__ cnt_g,
                                     const int2* __restrict__ edge_s,
                                     const float* __restrict__ h2s, const float* __restrict__ dinv,
                                     const float* __restrict__ b2, float* __restrict__ out) {
    int t = blockIdx.x * blockDim.x + threadIdx.x;
    int n = t >> 4;
    int sub = t & 15;
    if (n >= N_NODES) return;
    int s0 = start_g[n];
    int cnt = cnt_g[n];
    float acc = 0.0f;
    for (int j = sub; j < cnt; j += 16) {
        int2 m = edge_s[s0 + j];
        acc += __int_as_float(m.y) * h2s[m.x];   // dinv[src] already folded
    }
#pragma unroll
    for (int off = 8; off > 0; off >>= 1)
        acc += __shfl_down(acc, off, 16);
    if (sub == 0) {
        float z = dinv[n] * (acc + h2s[n]) + b2[0];
        out[n] = 1.0f / (1.0f + expf(-z));
    }
}

extern "C" void kernel_launch(void* const* d_in, const int* in_sizes, int n_in,
                              void* d_out, int out_size, void* d_ws, size_t ws_size,
                              hipStream_t stream) {
    const float* x  = (const float*)d_in[0];
    const int*   ei = (const int*)d_in[1];
    const float* ew = (const float*)d_in[2];
    const float* W1 = (const float*)d_in[3];
    const float* b1 = (const float*)d_in[4];
    const float* W2 = (const float*)d_in[5];
    const float* b2 = (const float*)d_in[6];
    float* out = (float*)d_out;

    const int* src = ei;
    const int* dst = ei + N_EDGES;

    // workspace layout (int2 arrays first for 8B alignment)
    char* ws = (char*)d_ws;
    int2*  edge_b  = (int2*)ws;              ws += (size_t)N_EDGES * sizeof(int2);
    int2*  edge_s  = (int2*)ws;              ws += (size_t)NBKT * BKT_CAP * sizeof(int2);
    int*   cnt2d   = (int*)ws;               ws += (size_t)NPASSC * NBKT * sizeof(int);
    int*   off2d   = (int*)ws;               ws += (size_t)NPASSC * NBKT * sizeof(int);
    int*   start_g = (int*)ws;               ws += N_NODES * sizeof(int);
    int*   cnt_g   = (int*)ws;               ws += N_NODES * sizeof(int);
    float* dinv    = (float*)ws;             ws += N_NODES * sizeof(float);
    float* h2s     = (float*)ws;             ws += N_NODES * sizeof(float);
    // align h1b to 128 B so each 64xbf16 row sits in a single cache line
    ws = (char*)(((uintptr_t)ws + 127) & ~(uintptr_t)127);
    __hip_bfloat16* h1b = (__hip_bfloat16*)ws;  // N_NODES * HID_DIM bf16

    // 4 dispatches, no memset, no global atomics anywhere
    partgemm_kernel<<<NPASSC + NGEMM, 256, 0, stream>>>(src, dst, ew, cnt2d, off2d, edge_b, x, W1, h1b);
    bsort_kernel<<<NBKT, 1024, 0, stream>>>(cnt2d, off2d, edge_b, edge_s, start_g, cnt_g, dinv);
    gather1_layer2_kernel<<<(N_NODES * 64) / 256, 256, 0, stream>>>(start_g, cnt_g, edge_s, h1b, dinv, b1, W2, h2s);
    gather2_final_kernel<<<(N_NODES * 16 + 255) / 256, 256, 0, stream>>>(start_g, cnt_g, edge_s, h2s, dinv, b2, out);
}